// Round 4
// baseline (164.947 us; speedup 1.0000x reference)
//
#include <hip/hip_runtime.h>

constexpr int NS = 64;          // samples
constexpr int NA = 64;          // agents per sample
constexpr int NN = NS * NA;     // 4096 nodes
constexpr int FD = 128;         // feature dim
constexpr int ZD = 2 * FD + 2;  // 258
constexpr int FS = 16;          // feature-slice width per block
constexpr int NB = NS * (FD / FS); // 512 blocks = (sample, f-slice)
constexpr int NT = 512;         // threads per block
constexpr int XPAD = 132;       // xs row stride: 528B = 33*16 (float4-aligned), +4 bank skew
constexpr float BN_EPS = 1e-5f;
constexpr float L2E = 1.44269504088896f;
constexpr float LN2 = 0.69314718055995f;

// Fused per-(sample, f-slice) CGConv layer body.
// GEMM: x from LDS (float4 chunks, 2 ds_read_b128 per 4k — was 8 ds_read_b32),
//       W straight from global row-major Wf/Ws (float2 pairs, L1-hot 33KB slice
//       shared by 64 blocks) — zero LDS traffic for weights, no pack stage.
// Then edge aggregation (exp-domain) + per-block BN partial stores (no atomics).
__device__ __forceinline__ void layer_body(
    const float (*xs)[XPAD], const float2* cs, float2 (*q)[FS],
    const float* __restrict__ Wf, const float* __restrict__ Ws,
    const float* __restrict__ bf, const float* __restrict__ bs,
    int tid, int s, int fq,
    float* __restrict__ agg, float* __restrict__ pS, float* __restrict__ pSS)
{
    const int fl = tid & (FS - 1);
    const int ig = tid >> 4;            // 0..31 -> nodes {ig, ig+32}
    const int f  = fq * FS + fl;
    const int base = s * NA;

    // f*ZD is even -> float2-aligned rows (ZD=258). k%4==0 -> k/2 offsets even.
    const float2* WfR = (const float2*)(Wf + f * ZD);
    const float2* WsR = (const float2*)(Ws + f * ZD);

    float aPf0=0.f,aQf0=0.f,aPs0=0.f,aQs0=0.f;
    float aPf1=0.f,aQf1=0.f,aPs1=0.f,aQs1=0.f;
    #pragma unroll 4
    for (int k = 0; k < FD; k += 4) {
        int h = k >> 1;
        float4 x0 = *(const float4*)&xs[ig][k];       // 4 rows/wave, bank-skewed
        float4 x1 = *(const float4*)&xs[ig + 32][k];
        float2 fA = WfR[h],      fB = WfR[h + 1];     // Wf[f][k..k+3]   (P gate)
        float2 fC = WfR[h + 64], fD = WfR[h + 65];    // Wf[f][k+128..]  (Q gate)
        float2 sA = WsR[h],      sB = WsR[h + 1];     // Ws[f][k..k+3]   (P soft)
        float2 sC = WsR[h + 64], sD = WsR[h + 65];    // Ws[f][k+128..]  (Q soft)
        aPf0 = fmaf(x0.x, fA.x, aPf0); aQf0 = fmaf(x0.x, fC.x, aQf0);
        aPs0 = fmaf(x0.x, sA.x, aPs0); aQs0 = fmaf(x0.x, sC.x, aQs0);
        aPf1 = fmaf(x1.x, fA.x, aPf1); aQf1 = fmaf(x1.x, fC.x, aQf1);
        aPs1 = fmaf(x1.x, sA.x, aPs1); aQs1 = fmaf(x1.x, sC.x, aQs1);

        aPf0 = fmaf(x0.y, fA.y, aPf0); aQf0 = fmaf(x0.y, fC.y, aQf0);
        aPs0 = fmaf(x0.y, sA.y, aPs0); aQs0 = fmaf(x0.y, sC.y, aQs0);
        aPf1 = fmaf(x1.y, fA.y, aPf1); aQf1 = fmaf(x1.y, fC.y, aQf1);
        aPs1 = fmaf(x1.y, sA.y, aPs1); aQs1 = fmaf(x1.y, sC.y, aQs1);

        aPf0 = fmaf(x0.z, fB.x, aPf0); aQf0 = fmaf(x0.z, fD.x, aQf0);
        aPs0 = fmaf(x0.z, sB.x, aPs0); aQs0 = fmaf(x0.z, sD.x, aQs0);
        aPf1 = fmaf(x1.z, fB.x, aPf1); aQf1 = fmaf(x1.z, fD.x, aQf1);
        aPs1 = fmaf(x1.z, sB.x, aPs1); aQs1 = fmaf(x1.z, sD.x, aQs1);

        aPf0 = fmaf(x0.w, fB.y, aPf0); aQf0 = fmaf(x0.w, fD.y, aQf0);
        aPs0 = fmaf(x0.w, sB.y, aPs0); aQs0 = fmaf(x0.w, sD.y, aQs0);
        aPf1 = fmaf(x1.w, fB.y, aPf1); aQf1 = fmaf(x1.w, fD.y, aQf1);
        aPs1 = fmaf(x1.w, sB.y, aPs1); aQs1 = fmaf(x1.w, sD.y, aQs1);
    }
    float we0 = Wf[f*ZD + 2*FD], we1 = Wf[f*ZD + 2*FD + 1];
    float ws0 = Ws[f*ZD + 2*FD], ws1 = Ws[f*ZD + 2*FD + 1];
    float bfv = bf[f], bsv = bs[f];
    float2 c0 = cs[ig], c1 = cs[ig + 32];
    float cf0 = c0.x*we0 + c0.y*we1, cg0 = c0.x*ws0 + c0.y*ws1;
    float cf1 = c1.x*we0 + c1.y*we1, cg1 = c1.x*ws0 + c1.y*ws1;
    float Pf0 = aPf0 + cf0 + bfv, Ps0 = aPs0 + cg0 + bsv;
    float Pf1 = aPf1 + cf1 + bfv, Ps1 = aPs1 + cg1 + bsv;
    float Qf0 = aQf0 - cf0,       Qs0 = aQs0 - cg0;
    float Qf1 = aQf1 - cf1,       Qs1 = aQs1 - cg1;
    // exp-domain: sigma = rcp(1 + e^{-P}e^{-Q}), softplus*log2e = log2(1 + e^{Ps}e^{Qs})
    float2 p0 = make_float2(__builtin_amdgcn_exp2f(-Pf0*L2E), __builtin_amdgcn_exp2f(Ps0*L2E));
    float2 p1 = make_float2(__builtin_amdgcn_exp2f(-Pf1*L2E), __builtin_amdgcn_exp2f(Ps1*L2E));
    q[ig][fl]    = make_float2(__builtin_amdgcn_exp2f(-Qf0*L2E), __builtin_amdgcn_exp2f(Qs0*L2E));
    q[ig+32][fl] = make_float2(__builtin_amdgcn_exp2f(-Qf1*L2E), __builtin_amdgcn_exp2f(Qs1*L2E));
    __syncthreads();

    // ---- edge aggregation: i in {ig, ig+32}, all 64 j, dual chains ----
    float a0=0.f, a1=0.f, b0=0.f, b1=0.f;
    #pragma unroll 4
    for (int j = 0; j < NA; j += 2) {
        float2 qa = q[j][fl];            // same-address bcast per lane-group: free
        float2 qb = q[j+1][fl];
        a0 = fmaf(__builtin_amdgcn_rcpf(1.0f + p0.x*qa.x),
                  __builtin_amdgcn_logf(1.0f + p0.y*qa.y), a0);
        b0 = fmaf(__builtin_amdgcn_rcpf(1.0f + p1.x*qa.x),
                  __builtin_amdgcn_logf(1.0f + p1.y*qa.y), b0);
        a1 = fmaf(__builtin_amdgcn_rcpf(1.0f + p0.x*qb.x),
                  __builtin_amdgcn_logf(1.0f + p0.y*qb.y), a1);
        b1 = fmaf(__builtin_amdgcn_rcpf(1.0f + p1.x*qb.x),
                  __builtin_amdgcn_logf(1.0f + p1.y*qb.y), b1);
    }
    float aA = a0 + a1, aB = b0 + b1;
    {   // remove self-loop terms (j == i)
        float2 qv0 = q[ig][fl];
        aA -= __builtin_amdgcn_rcpf(1.0f + p0.x*qv0.x) *
              __builtin_amdgcn_logf(1.0f + p0.y*qv0.y);
        float2 qv1 = q[ig+32][fl];
        aB -= __builtin_amdgcn_rcpf(1.0f + p1.x*qv1.x) *
              __builtin_amdgcn_logf(1.0f + p1.y*qv1.y);
    }
    aA *= LN2; aB *= LN2;               // log2 -> ln once, outside the sum
    agg[(base + ig) * FD + f]      = aA;
    agg[(base + ig + 32) * FD + f] = aB;

    // ---- BN partial stats: reduce 64 i per f in-block, plain stores ----
    __syncthreads();                    // all q reads done; alias as scratch
    float* sm = (float*)q;              // 2048 floats available, need 1024
    sm[tid]      = aA + aB;
    sm[NT + tid] = aA*aA + aB*aB;
    __syncthreads();
    if (tid < FS) {
        float sv = 0.f, qv = 0.f;
        #pragma unroll
        for (int r = 0; r < 32; ++r) {
            sv += sm[r * FS + tid];
            qv += sm[NT + r * FS + tid];
        }
        pS [s * FD + fq * FS + tid] = sv;   // distinct slot per block: no atomics
        pSS[s * FD + fq * FS + tid] = qv;
    }
}

// Layer 1: stage x0 tile, fused GEMM+edge -> agg1 + partial stats1.
__global__ __launch_bounds__(NT) void layer1_kernel(
    const float* __restrict__ X0, const float* __restrict__ C,
    const float* __restrict__ Wf, const float* __restrict__ Ws,
    const float* __restrict__ bf, const float* __restrict__ bs,
    float* __restrict__ agg, float* __restrict__ pS, float* __restrict__ pSS)
{
    __shared__ __align__(16) float xs[NA][XPAD];  // 33 KB
    __shared__ float2 q[NA][FS];                  //  8 KB
    __shared__ float2 cs[NA];                     // 0.5 KB
    int tid = threadIdx.x, bid = blockIdx.x;
    int s = bid & (NS - 1), fq = bid >> 6;  // 8 f-slices of a sample -> same XCD
    int base = s * NA;
    const float4* Xv = (const float4*)(X0 + base * FD);
    for (int idx = tid; idx < NA * FD / 4; idx += NT) {
        int n = idx >> 5, k4 = idx & 31;
        *(float4*)&xs[n][k4 * 4] = Xv[idx];
    }
    if (tid < NA) cs[tid] = ((const float2*)C)[base + tid];
    __syncthreads();
    layer_body(xs, cs, q, Wf, Ws, bf, bs, tid, s, fq, agg, pS, pSS);
}

// Layer 2: parallel BN1 partial reduction (512 threads), x1 = relu(BN1(agg1)+x0)
// staged into LDS + global, then fused layer -> agg2 + partial stats2.
__global__ __launch_bounds__(NT) void layer2_kernel(
    const float* __restrict__ X0, const float* __restrict__ agg1,
    const float* __restrict__ C,
    const float* __restrict__ pS1, const float* __restrict__ pSS1,
    const float* __restrict__ g1, const float* __restrict__ be1,
    const float* __restrict__ Wf, const float* __restrict__ Ws,
    const float* __restrict__ bf, const float* __restrict__ bs,
    float* __restrict__ x1, float* __restrict__ agg2,
    float* __restrict__ pS2, float* __restrict__ pSS2)
{
    __shared__ __align__(16) float xs[NA][XPAD];
    __shared__ float2 q[NA][FS];
    __shared__ float2 cs[NA];
    __shared__ float bnsc[FD], bnsh[FD];
    int tid = threadIdx.x, bid = blockIdx.x;
    int s = bid & (NS - 1), fq = bid >> 6;
    int base = s * NA;
    // stats1 reduce, all 512 threads: thread (fr = tid&127, sq = tid>>7) sums 16 samples
    {
        int fr = tid & (FD - 1), sq = tid >> 7;
        float sv = 0.f, qv = 0.f;
        #pragma unroll
        for (int s2 = 0; s2 < NS / 4; ++s2) {
            int si = sq * (NS / 4) + s2;
            sv += pS1[si * FD + fr];
            qv += pSS1[si * FD + fr];
        }
        float* sm = (float*)q;          // 2048-float scratch (dead until q writes)
        sm[tid] = sv;
        sm[NT + tid] = qv;
    }
    if (tid < NA) cs[tid] = ((const float2*)C)[base + tid];
    __syncthreads();
    if (tid < FD) {
        const float* sm = (const float*)q;
        float sv = sm[tid] + sm[FD + tid] + sm[2*FD + tid] + sm[3*FD + tid];
        float qv = sm[NT + tid] + sm[NT + FD + tid] + sm[NT + 2*FD + tid] + sm[NT + 3*FD + tid];
        float m  = sv * (1.0f / NN);
        float v  = qv * (1.0f / NN) - m * m;
        float sc = g1[tid] * rsqrtf(v + BN_EPS);
        bnsc[tid] = sc;
        bnsh[tid] = be1[tid] - m * sc;
    }
    __syncthreads();
    const float4* Xv  = (const float4*)(X0 + base * FD);
    const float4* Av  = (const float4*)(agg1 + base * FD);
    float4*       X1v = (float4*)(x1 + base * FD);
    for (int idx = tid; idx < NA * FD / 4; idx += NT) {
        int n = idx >> 5, k4 = (idx & 31) * 4;
        float4 x = Xv[idx], a = Av[idx];
        float4 r;
        r.x = fmaxf(fmaf(a.x, bnsc[k4 + 0], bnsh[k4 + 0]) + x.x, 0.0f);
        r.y = fmaxf(fmaf(a.y, bnsc[k4 + 1], bnsh[k4 + 1]) + x.y, 0.0f);
        r.z = fmaxf(fmaf(a.z, bnsc[k4 + 2], bnsh[k4 + 2]) + x.z, 0.0f);
        r.w = fmaxf(fmaf(a.w, bnsc[k4 + 3], bnsh[k4 + 3]) + x.w, 0.0f);
        *(float4*)&xs[n][k4] = r;
        X1v[idx] = r;                   // x1 for the epilogue kernel
    }
    __syncthreads();
    layer_body(xs, cs, q, Wf, Ws, bf, bs, tid, s, fq, agg2, pS2, pSS2);
}

// Epilogue: reduce BN2 partials per block, out = relu(BN2(agg2) + x1).
__global__ __launch_bounds__(NT) void out_kernel(
    const float4* __restrict__ x1, const float4* __restrict__ agg2,
    const float* __restrict__ pS2, const float* __restrict__ pSS2,
    const float* __restrict__ g2, const float* __restrict__ be2,
    float4* __restrict__ out)
{
    __shared__ float sc[FD], sh[FD];
    int tid = threadIdx.x;
    if (tid < FD) {
        float sv = 0.f, qv = 0.f;
        #pragma unroll
        for (int s2 = 0; s2 < NS; ++s2) {
            sv += pS2[s2 * FD + tid];
            qv += pSS2[s2 * FD + tid];
        }
        float m  = sv * (1.0f / NN);
        float v  = qv * (1.0f / NN) - m * m;
        float scl = g2[tid] * rsqrtf(v + BN_EPS);
        sc[tid] = scl;
        sh[tid] = be2[tid] - m * scl;
    }
    __syncthreads();
    int idx = blockIdx.x * NT + tid;    // < NN*FD/4
    int f0 = (idx & 31) * 4;
    float4 xv = x1[idx], av = agg2[idx];
    float4 r;
    r.x = fmaxf(fmaf(av.x, sc[f0 + 0], sh[f0 + 0]) + xv.x, 0.0f);
    r.y = fmaxf(fmaf(av.y, sc[f0 + 1], sh[f0 + 1]) + xv.y, 0.0f);
    r.z = fmaxf(fmaf(av.z, sc[f0 + 2], sh[f0 + 2]) + xv.z, 0.0f);
    r.w = fmaxf(fmaf(av.w, sc[f0 + 3], sh[f0 + 3]) + xv.w, 0.0f);
    out[idx] = r;
}

extern "C" void kernel_launch(void* const* d_in, const int* in_sizes, int n_in,
                              void* d_out, int out_size, void* d_ws, size_t ws_size,
                              hipStream_t stream) {
    const float* gnn_in  = (const float*)d_in[0];
    const float* centers = (const float*)d_in[1];
    // d_in[2]=src, d_in[3]=dst: structure known (fully connected per sample) — unused
    const float* Wf1 = (const float*)d_in[4];
    const float* bf1 = (const float*)d_in[5];
    const float* Ws1 = (const float*)d_in[6];
    const float* bs1 = (const float*)d_in[7];
    const float* g1  = (const float*)d_in[8];
    const float* be1 = (const float*)d_in[9];
    const float* Wf2 = (const float*)d_in[10];
    const float* bf2 = (const float*)d_in[11];
    const float* Ws2 = (const float*)d_in[12];
    const float* bs2 = (const float*)d_in[13];
    const float* g2  = (const float*)d_in[14];
    const float* be2 = (const float*)d_in[15];

    char* ws = (char*)d_ws;
    float* agg1  = (float*)(ws);                             // 2 MB
    float* agg2  = (float*)(ws + (2 << 20));                 // 2 MB
    float* x1    = (float*)(ws + (4 << 20));                 // 2 MB
    float* p1S   = (float*)(ws + (6 << 20));                 // 32 KB
    float* p1SS  = (float*)(ws + (6 << 20) + (32 << 10));    // 32 KB
    float* p2S   = (float*)(ws + (6 << 20) + (64 << 10));    // 32 KB
    float* p2SS  = (float*)(ws + (6 << 20) + (96 << 10));    // 32 KB

    layer1_kernel<<<NB, NT, 0, stream>>>(gnn_in, centers, Wf1, Ws1, bf1, bs1,
                                         agg1, p1S, p1SS);
    layer2_kernel<<<NB, NT, 0, stream>>>(gnn_in, agg1, centers, p1S, p1SS, g1, be1,
                                         Wf2, Ws2, bf2, bs2, x1, agg2, p2S, p2SS);
    out_kernel<<<NN * FD / 4 / NT, NT, 0, stream>>>(
        (const float4*)x1, (const float4*)agg2, p2S, p2SS, g2, be2, (float4*)d_out);
}

// Round 5
// 145.930 us; speedup vs baseline: 1.1303x; 1.1303x over previous
//
#include <hip/hip_runtime.h>

constexpr int NS = 64;          // samples
constexpr int NA = 64;          // agents per sample
constexpr int NN = NS * NA;     // 4096 nodes
constexpr int FD = 128;         // feature dim
constexpr int ZD = 2 * FD + 2;  // 258
constexpr int FS = 16;          // feature-slice width per block
constexpr int NB = NS * (FD / FS); // 512 blocks = (sample, f-slice)
constexpr int NT = 512;         // threads per block
constexpr int XPAD = 132;       // xs row stride: 528B = 33*16 (float4-aligned), +4 bank skew
constexpr float BN_EPS = 1e-5f;
constexpr float L2E = 1.44269504088896f;
constexpr float LN2 = 0.69314718055995f;

// Benign-race self-pack: every block writes its OWN f-slice of PK[k][f] =
// {Wf[f][k], Wf[f][k+128], Ws[f][k], Ws[f][k+128]} (float4, coalesced stores).
// The 64 blocks sharing a slice write byte-identical data, and each block only
// READS entries it wrote itself (after __syncthreads' vmcnt drain) -> no
// cross-block dependency, no pack launch. GEMM then streams PK via the VMEM
// pipe: 256B contiguous per wave, 4-way lane-group broadcast, L1-resident.
__device__ __forceinline__ void selfpack_w(
    float4* __restrict__ PK,
    const float* __restrict__ Wf, const float* __restrict__ Ws,
    int fq, int tid)
{
    for (int i = tid; i < FD * FS; i += NT) {
        int k = i >> 4, fr = i & (FS - 1);
        int f = fq * FS + fr;
        PK[k * FD + f] = make_float4(Wf[f * ZD + k], Wf[f * ZD + FD + k],
                                     Ws[f * ZD + k], Ws[f * ZD + FD + k]);
    }
}

// Fused per-(sample, f-slice) CGConv layer body.
// GEMM: x from LDS (float4, 2 ds_read_b128 per 4k), W from packed global PK
// (VMEM pipe, L1-hot) -> LDS pipe carries only x. Then edge aggregation
// (exp-domain) + per-block BN partial stores (no atomics).
__device__ __forceinline__ void layer_body(
    const float (*xs)[XPAD], const float2* cs, float2 (*q)[FS],
    const float4* __restrict__ PK,
    const float* __restrict__ Wf, const float* __restrict__ Ws,
    const float* __restrict__ bf, const float* __restrict__ bs,
    int tid, int s, int fq,
    float* __restrict__ agg, float* __restrict__ pS, float* __restrict__ pSS)
{
    const int fl = tid & (FS - 1);
    const int ig = tid >> 4;            // 0..31 -> nodes {ig, ig+32}
    const int f  = fq * FS + fl;
    const int base = s * NA;
    const float4* Wp = PK + f;          // PK[k][f]: wave reads 256B contiguous

    float aPf0=0.f,aQf0=0.f,aPs0=0.f,aQs0=0.f;
    float aPf1=0.f,aQf1=0.f,aPs1=0.f,aQs1=0.f;
    #pragma unroll 2
    for (int k = 0; k < FD; k += 4) {
        float4 x0 = *(const float4*)&xs[ig][k];       // 4 rows/wave, bank-skewed
        float4 x1 = *(const float4*)&xs[ig + 32][k];
        float4 w0 = Wp[(k + 0) * FD];
        float4 w1 = Wp[(k + 1) * FD];
        float4 w2 = Wp[(k + 2) * FD];
        float4 w3 = Wp[(k + 3) * FD];
        aPf0 = fmaf(x0.x, w0.x, aPf0); aQf0 = fmaf(x0.x, w0.y, aQf0);
        aPs0 = fmaf(x0.x, w0.z, aPs0); aQs0 = fmaf(x0.x, w0.w, aQs0);
        aPf1 = fmaf(x1.x, w0.x, aPf1); aQf1 = fmaf(x1.x, w0.y, aQf1);
        aPs1 = fmaf(x1.x, w0.z, aPs1); aQs1 = fmaf(x1.x, w0.w, aQs1);

        aPf0 = fmaf(x0.y, w1.x, aPf0); aQf0 = fmaf(x0.y, w1.y, aQf0);
        aPs0 = fmaf(x0.y, w1.z, aPs0); aQs0 = fmaf(x0.y, w1.w, aQs0);
        aPf1 = fmaf(x1.y, w1.x, aPf1); aQf1 = fmaf(x1.y, w1.y, aQf1);
        aPs1 = fmaf(x1.y, w1.z, aPs1); aQs1 = fmaf(x1.y, w1.w, aQs1);

        aPf0 = fmaf(x0.z, w2.x, aPf0); aQf0 = fmaf(x0.z, w2.y, aQf0);
        aPs0 = fmaf(x0.z, w2.z, aPs0); aQs0 = fmaf(x0.z, w2.w, aQs0);
        aPf1 = fmaf(x1.z, w2.x, aPf1); aQf1 = fmaf(x1.z, w2.y, aQf1);
        aPs1 = fmaf(x1.z, w2.z, aPs1); aQs1 = fmaf(x1.z, w2.w, aQs1);

        aPf0 = fmaf(x0.w, w3.x, aPf0); aQf0 = fmaf(x0.w, w3.y, aQf0);
        aPs0 = fmaf(x0.w, w3.z, aPs0); aQs0 = fmaf(x0.w, w3.w, aQs0);
        aPf1 = fmaf(x1.w, w3.x, aPf1); aQf1 = fmaf(x1.w, w3.y, aQf1);
        aPs1 = fmaf(x1.w, w3.z, aPs1); aQs1 = fmaf(x1.w, w3.w, aQs1);
    }
    float we0 = Wf[f*ZD + 2*FD], we1 = Wf[f*ZD + 2*FD + 1];
    float ws0 = Ws[f*ZD + 2*FD], ws1 = Ws[f*ZD + 2*FD + 1];
    float bfv = bf[f], bsv = bs[f];
    float2 c0 = cs[ig], c1 = cs[ig + 32];
    float cf0 = c0.x*we0 + c0.y*we1, cg0 = c0.x*ws0 + c0.y*ws1;
    float cf1 = c1.x*we0 + c1.y*we1, cg1 = c1.x*ws0 + c1.y*ws1;
    float Pf0 = aPf0 + cf0 + bfv, Ps0 = aPs0 + cg0 + bsv;
    float Pf1 = aPf1 + cf1 + bfv, Ps1 = aPs1 + cg1 + bsv;
    float Qf0 = aQf0 - cf0,       Qs0 = aQs0 - cg0;
    float Qf1 = aQf1 - cf1,       Qs1 = aQs1 - cg1;
    // exp-domain: sigma = rcp(1 + e^{-P}e^{-Q}), softplus*log2e = log2(1 + e^{Ps}e^{Qs})
    float2 p0 = make_float2(__builtin_amdgcn_exp2f(-Pf0*L2E), __builtin_amdgcn_exp2f(Ps0*L2E));
    float2 p1 = make_float2(__builtin_amdgcn_exp2f(-Pf1*L2E), __builtin_amdgcn_exp2f(Ps1*L2E));
    q[ig][fl]    = make_float2(__builtin_amdgcn_exp2f(-Qf0*L2E), __builtin_amdgcn_exp2f(Qs0*L2E));
    q[ig+32][fl] = make_float2(__builtin_amdgcn_exp2f(-Qf1*L2E), __builtin_amdgcn_exp2f(Qs1*L2E));
    __syncthreads();

    // ---- edge aggregation: i in {ig, ig+32}, all 64 j, dual chains ----
    float a0=0.f, a1=0.f, b0=0.f, b1=0.f;
    #pragma unroll 4
    for (int j = 0; j < NA; j += 2) {
        float2 qa = q[j][fl];            // same-address bcast per lane-group: free
        float2 qb = q[j+1][fl];
        a0 = fmaf(__builtin_amdgcn_rcpf(1.0f + p0.x*qa.x),
                  __builtin_amdgcn_logf(1.0f + p0.y*qa.y), a0);
        b0 = fmaf(__builtin_amdgcn_rcpf(1.0f + p1.x*qa.x),
                  __builtin_amdgcn_logf(1.0f + p1.y*qa.y), b0);
        a1 = fmaf(__builtin_amdgcn_rcpf(1.0f + p0.x*qb.x),
                  __builtin_amdgcn_logf(1.0f + p0.y*qb.y), a1);
        b1 = fmaf(__builtin_amdgcn_rcpf(1.0f + p1.x*qb.x),
                  __builtin_amdgcn_logf(1.0f + p1.y*qb.y), b1);
    }
    float aA = a0 + a1, aB = b0 + b1;
    {   // remove self-loop terms (j == i)
        float2 qv0 = q[ig][fl];
        aA -= __builtin_amdgcn_rcpf(1.0f + p0.x*qv0.x) *
              __builtin_amdgcn_logf(1.0f + p0.y*qv0.y);
        float2 qv1 = q[ig+32][fl];
        aB -= __builtin_amdgcn_rcpf(1.0f + p1.x*qv1.x) *
              __builtin_amdgcn_logf(1.0f + p1.y*qv1.y);
    }
    aA *= LN2; aB *= LN2;               // log2 -> ln once, outside the sum
    agg[(base + ig) * FD + f]      = aA;
    agg[(base + ig + 32) * FD + f] = aB;

    // ---- BN partial stats: reduce 64 i per f in-block, plain stores ----
    __syncthreads();                    // all q reads done; alias as scratch
    float* sm = (float*)q;              // 2048 floats available, need 1024
    sm[tid]      = aA + aB;
    sm[NT + tid] = aA*aA + aB*aB;
    __syncthreads();
    if (tid < FS) {
        float sv = 0.f, qv = 0.f;
        #pragma unroll
        for (int r = 0; r < 32; ++r) {
            sv += sm[r * FS + tid];
            qv += sm[NT + r * FS + tid];
        }
        pS [s * FD + fq * FS + tid] = sv;   // distinct slot per block: no atomics
        pSS[s * FD + fq * FS + tid] = qv;
    }
}

// Layer 1: self-pack W1 slice -> global PK1, stage x0 tile, fused GEMM+edge.
__global__ __launch_bounds__(NT) void layer1_kernel(
    const float* __restrict__ X0, const float* __restrict__ C,
    const float* __restrict__ Wf, const float* __restrict__ Ws,
    const float* __restrict__ bf, const float* __restrict__ bs,
    float4* __restrict__ PK,
    float* __restrict__ agg, float* __restrict__ pS, float* __restrict__ pSS)
{
    __shared__ __align__(16) float xs[NA][XPAD];  // 33 KB
    __shared__ float2 q[NA][FS];                  //  8 KB
    __shared__ float2 cs[NA];                     // 0.5 KB
    int tid = threadIdx.x, bid = blockIdx.x;
    int s = bid & (NS - 1), fq = bid >> 6;  // 8 f-slices of a sample -> same XCD
    int base = s * NA;
    selfpack_w(PK, Wf, Ws, fq, tid);
    const float4* Xv = (const float4*)(X0 + base * FD);
    for (int idx = tid; idx < NA * FD / 4; idx += NT) {
        int n = idx >> 5, k4 = idx & 31;
        *(float4*)&xs[n][k4 * 4] = Xv[idx];
    }
    if (tid < NA) cs[tid] = ((const float2*)C)[base + tid];
    __threadfence_block();
    __syncthreads();                    // drains vmcnt: own PK stores visible
    layer_body(xs, cs, q, PK, Wf, Ws, bf, bs, tid, s, fq, agg, pS, pSS);
}

// Layer 2: self-pack W2 slice, parallel BN1 partial reduce, x1 = relu(BN1+x0)
// staged into LDS + global, then fused layer -> agg2 + partial stats2.
__global__ __launch_bounds__(NT) void layer2_kernel(
    const float* __restrict__ X0, const float* __restrict__ agg1,
    const float* __restrict__ C,
    const float* __restrict__ pS1, const float* __restrict__ pSS1,
    const float* __restrict__ g1, const float* __restrict__ be1,
    const float* __restrict__ Wf, const float* __restrict__ Ws,
    const float* __restrict__ bf, const float* __restrict__ bs,
    float4* __restrict__ PK,
    float* __restrict__ x1, float* __restrict__ agg2,
    float* __restrict__ pS2, float* __restrict__ pSS2)
{
    __shared__ __align__(16) float xs[NA][XPAD];
    __shared__ float2 q[NA][FS];
    __shared__ float2 cs[NA];
    __shared__ float bnsc[FD], bnsh[FD];
    int tid = threadIdx.x, bid = blockIdx.x;
    int s = bid & (NS - 1), fq = bid >> 6;
    int base = s * NA;
    selfpack_w(PK, Wf, Ws, fq, tid);
    // stats1 reduce, all 512 threads: thread (fr = tid&127, sq = tid>>7) sums 16 samples
    {
        int fr = tid & (FD - 1), sq = tid >> 7;
        float sv = 0.f, qv = 0.f;
        #pragma unroll
        for (int s2 = 0; s2 < NS / 4; ++s2) {
            int si = sq * (NS / 4) + s2;
            sv += pS1[si * FD + fr];
            qv += pSS1[si * FD + fr];
        }
        float* sm = (float*)q;          // 2048-float scratch (dead until q writes)
        sm[tid] = sv;
        sm[NT + tid] = qv;
    }
    if (tid < NA) cs[tid] = ((const float2*)C)[base + tid];
    __threadfence_block();
    __syncthreads();                    // PK stores + scratch visible
    if (tid < FD) {
        const float* sm = (const float*)q;
        float sv = sm[tid] + sm[FD + tid] + sm[2*FD + tid] + sm[3*FD + tid];
        float qv = sm[NT + tid] + sm[NT + FD + tid] + sm[NT + 2*FD + tid] + sm[NT + 3*FD + tid];
        float m  = sv * (1.0f / NN);
        float v  = qv * (1.0f / NN) - m * m;
        float sc = g1[tid] * rsqrtf(v + BN_EPS);
        bnsc[tid] = sc;
        bnsh[tid] = be1[tid] - m * sc;
    }
    __syncthreads();
    const float4* Xv  = (const float4*)(X0 + base * FD);
    const float4* Av  = (const float4*)(agg1 + base * FD);
    float4*       X1v = (float4*)(x1 + base * FD);
    for (int idx = tid; idx < NA * FD / 4; idx += NT) {
        int n = idx >> 5, k4 = (idx & 31) * 4;
        float4 x = Xv[idx], a = Av[idx];
        float4 r;
        r.x = fmaxf(fmaf(a.x, bnsc[k4 + 0], bnsh[k4 + 0]) + x.x, 0.0f);
        r.y = fmaxf(fmaf(a.y, bnsc[k4 + 1], bnsh[k4 + 1]) + x.y, 0.0f);
        r.z = fmaxf(fmaf(a.z, bnsc[k4 + 2], bnsh[k4 + 2]) + x.z, 0.0f);
        r.w = fmaxf(fmaf(a.w, bnsc[k4 + 3], bnsh[k4 + 3]) + x.w, 0.0f);
        *(float4*)&xs[n][k4] = r;
        X1v[idx] = r;                   // x1 for the epilogue kernel
    }
    __syncthreads();
    layer_body(xs, cs, q, PK, Wf, Ws, bf, bs, tid, s, fq, agg2, pS2, pSS2);
}

// Epilogue: reduce BN2 partials per block, out = relu(BN2(agg2) + x1).
__global__ __launch_bounds__(NT) void out_kernel(
    const float4* __restrict__ x1, const float4* __restrict__ agg2,
    const float* __restrict__ pS2, const float* __restrict__ pSS2,
    const float* __restrict__ g2, const float* __restrict__ be2,
    float4* __restrict__ out)
{
    __shared__ float sc[FD], sh[FD];
    int tid = threadIdx.x;
    if (tid < FD) {
        float sv = 0.f, qv = 0.f;
        #pragma unroll
        for (int s2 = 0; s2 < NS; ++s2) {
            sv += pS2[s2 * FD + tid];
            qv += pSS2[s2 * FD + tid];
        }
        float m  = sv * (1.0f / NN);
        float v  = qv * (1.0f / NN) - m * m;
        float scl = g2[tid] * rsqrtf(v + BN_EPS);
        sc[tid] = scl;
        sh[tid] = be2[tid] - m * scl;
    }
    __syncthreads();
    int idx = blockIdx.x * NT + tid;    // < NN*FD/4
    int f0 = (idx & 31) * 4;
    float4 xv = x1[idx], av = agg2[idx];
    float4 r;
    r.x = fmaxf(fmaf(av.x, sc[f0 + 0], sh[f0 + 0]) + xv.x, 0.0f);
    r.y = fmaxf(fmaf(av.y, sc[f0 + 1], sh[f0 + 1]) + xv.y, 0.0f);
    r.z = fmaxf(fmaf(av.z, sc[f0 + 2], sh[f0 + 2]) + xv.z, 0.0f);
    r.w = fmaxf(fmaf(av.w, sc[f0 + 3], sh[f0 + 3]) + xv.w, 0.0f);
    out[idx] = r;
}

extern "C" void kernel_launch(void* const* d_in, const int* in_sizes, int n_in,
                              void* d_out, int out_size, void* d_ws, size_t ws_size,
                              hipStream_t stream) {
    const float* gnn_in  = (const float*)d_in[0];
    const float* centers = (const float*)d_in[1];
    // d_in[2]=src, d_in[3]=dst: structure known (fully connected per sample) — unused
    const float* Wf1 = (const float*)d_in[4];
    const float* bf1 = (const float*)d_in[5];
    const float* Ws1 = (const float*)d_in[6];
    const float* bs1 = (const float*)d_in[7];
    const float* g1  = (const float*)d_in[8];
    const float* be1 = (const float*)d_in[9];
    const float* Wf2 = (const float*)d_in[10];
    const float* bf2 = (const float*)d_in[11];
    const float* Ws2 = (const float*)d_in[12];
    const float* bs2 = (const float*)d_in[13];
    const float* g2  = (const float*)d_in[14];
    const float* be2 = (const float*)d_in[15];

    char* ws = (char*)d_ws;
    float4* PK1  = (float4*)(ws);                            // 256 KB
    float4* PK2  = (float4*)(ws + (256 << 10));              // 256 KB
    float* agg1  = (float*)(ws + (512 << 10));               // 2 MB
    float* agg2  = (float*)(ws + (512 << 10) + (2 << 20));   // 2 MB
    float* x1    = (float*)(ws + (512 << 10) + (4 << 20));   // 2 MB
    float* p1S   = (float*)(ws + (512 << 10) + (6 << 20));                 // 32 KB
    float* p1SS  = (float*)(ws + (512 << 10) + (6 << 20) + (32 << 10));    // 32 KB
    float* p2S   = (float*)(ws + (512 << 10) + (6 << 20) + (64 << 10));    // 32 KB
    float* p2SS  = (float*)(ws + (512 << 10) + (6 << 20) + (96 << 10));    // 32 KB

    layer1_kernel<<<NB, NT, 0, stream>>>(gnn_in, centers, Wf1, Ws1, bf1, bs1,
                                         PK1, agg1, p1S, p1SS);
    layer2_kernel<<<NB, NT, 0, stream>>>(gnn_in, agg1, centers, p1S, p1SS, g1, be1,
                                         Wf2, Ws2, bf2, bs2, PK2, x1, agg2, p2S, p2SS);
    out_kernel<<<NN * FD / 4 / NT, NT, 0, stream>>>(
        (const float4*)x1, (const float4*)agg2, p2S, p2SS, g2, be2, (float4*)d_out);
}